// Round 3
// baseline (430.444 us; speedup 1.0000x reference)
//
#include <hip/hip_runtime.h>
#include <hip/hip_bf16.h>

// Problem: B=4,S=4096 tokens (16384), HIDDEN=1024, 16 heads x 64 dim.
// "Attention" mixes HEADS per token (16x16 softmax over heads), not sequence.
// Inputs/output fp32; compute bf16-MFMA w/ fp32 accumulate.
//
// R7 -> R8 (R7: 291.4us; QKV 125us, MfmaUtil 34%, FETCH 94MB):
//  GEMM: (a) revert XCD swizzle (R6 mapping, FETCH 73.8MB proven);
//  (b) operand swap (A-op=W, B-op=x) + wave tiles 4m-quarter x 2n-half:
//      x-frags loaded ONCE per tile (P0) into regs; W-frags 4/phase;
//      phases P0..P3 read B-half 0,1,0,1; A-halves dead after P0.
//      vmcnt ledger: end-P0 VMCNT(4) covers B1(t); end-P3 VMCNT(2) covers
//      A,B0(t+1); T-1 drains. WAR distance >=3 barriers everywhere.
//  (c) epilogue: D is n-contiguous per lane after swap. bf16: pack 4 ->
//      ds_write_b64 into 128KB LDS C-tile (chunk ^= m&15) -> 512B-coalesced
//      row stores (1 row/wave-instr). f32: direct dwordx4 (64B runs).
//  ATTN (~97us by subtraction vs ~25us floor, both rounds): stage 6KB qkv
//  row via 6 global_load_lds (pre-swizzled source, per-wave vmcnt, no
//  barriers); Q/K frags = GEMM's conflict-free LDS pattern; PV operand swap
//  -> O d-contiguous -> b64 pack -> swizzled 2KB O-tile -> 512B stores.
//  Global VMEM instrs/wave: ~56 -> 10.

typedef __bf16 bf16;
typedef __attribute__((ext_vector_type(8))) __bf16 bf16x8;
typedef __attribute__((ext_vector_type(4))) float floatx4;

#define HIDDEN 1024
#define BM 128
#define BN 128
#define BK 32

#define VMCNT(N) asm volatile("s_waitcnt vmcnt(" #N ")" ::: "memory")
#define LGKM0()                                                                \
    do {                                                                       \
        asm volatile("s_waitcnt lgkmcnt(0)" ::: "memory");                     \
        __builtin_amdgcn_sched_barrier(0);                                     \
    } while (0)
#define SBAR() __builtin_amdgcn_s_barrier()

__device__ __forceinline__ void async_load16(const bf16* g, bf16* lds) {
    __builtin_amdgcn_global_load_lds(
        (const __attribute__((address_space(1))) void*)g,
        (__attribute__((address_space(3))) void*)lds, 16, 0, 0);
}

__device__ __forceinline__ bf16x8 load8(const bf16* p) {
    return *(const bf16x8*)p;
}
__device__ __forceinline__ bf16x8 load8(const float* p) {
    floatx4 lo = *(const floatx4*)p;
    floatx4 hi = *(const floatx4*)(p + 4);
    bf16x8 r;
#pragma unroll
    for (int i = 0; i < 4; ++i) { r[i] = (bf16)lo[i]; r[i + 4] = (bf16)hi[i]; }
    return r;
}

// ---------- one-time fp32 -> bf16 conversion: x then packed wq|wk|wv|wo ----
__global__ __launch_bounds__(256) void cvt_all(
    const float* __restrict__ x,
    const float* __restrict__ wq, const float* __restrict__ wk,
    const float* __restrict__ wv, const float* __restrict__ wo,
    bf16* __restrict__ xb, bf16* __restrict__ wpk, int mh8)
{
    const int per = (HIDDEN * HIDDEN) / 8;   // 131072 chunks per weight
    int i = blockIdx.x * 256 + threadIdx.x;
    if (i < mh8) {
        *(bf16x8*)&xb[(size_t)i * 8] = load8(&x[(size_t)i * 8]);
    } else {
        int j = i - mh8;
        int wsel = j / per;
        int off  = (j - wsel * per) * 8;
        const float* s = wsel == 0 ? wq : wsel == 1 ? wk : wsel == 2 ? wv : wo;
        *(bf16x8*)&wpk[(size_t)j * 8] = load8(&s[off]);
    }
}

// ---------- 256^2 8-phase GEMM, swapped operands ------------------------
// C[m,n] = sum_k A[m,k]*W[n,k]. 512 thr = 8 waves: wm4=w&3 (m-quarter 64),
// wn2=w>>2 (n-half 128). MFMA: A-op = W-frag, B-op = x-frag ->
// D[quad*4+r -> n][col -> m] (n-contiguous per lane).

// stage one 16KB half-tile. S=64: A halves by m-bit6; S=32: B by n-bit5.
template <int S>
__device__ __forceinline__ void stage_half(const bf16* __restrict__ gbase,
                                           int ld, int kt, bf16* lhalf,
                                           int h, int tid) {
#pragma unroll
    for (int j = 0; j < 2; ++j) {
        const int ci = j * 512 + tid;
        const int rr = ci >> 3;
        const int cs = (ci & 7) ^ (rr & 7);
        const int gr = h * S + (rr & (S - 1)) + (rr >> (S == 64 ? 6 : 5)) * (2 * S);
        async_load16(&gbase[(size_t)gr * ld + kt + cs * 8], &lhalf[ci * 8]);
    }
}

// x-frags: 4 (ni) x 2 (kk) from the wave's single A-half, held all tile.
__device__ __forceinline__ void ld_x8(const bf16* h, int wmh, int col, int quad,
                                      int cx, bf16x8 (&xf)[4][2]) {
#pragma unroll
    for (int ni = 0; ni < 4; ++ni) {
        const int rr = wmh * 64 + ni * 16 + col;
#pragma unroll
        for (int kk = 0; kk < 2; ++kk)
            xf[ni][kk] = *(const bf16x8*)&h[rr * 64 + (((kk << 2) + quad) ^ cx) * 8];
    }
}
// W-frags: 2 (mi) x 2 (kk) for one phase.
__device__ __forceinline__ void ld_w2(const bf16* h, int rbase, int col, int quad,
                                      int cx, bf16x8 (&wf)[2][2]) {
#pragma unroll
    for (int i = 0; i < 2; ++i) {
        const int rr = rbase + i * 16 + col;
#pragma unroll
        for (int kk = 0; kk < 2; ++kk)
            wf[i][kk] = *(const bf16x8*)&h[rr * 64 + (((kk << 2) + quad) ^ cx) * 8];
    }
}

template <int P>
__device__ __forceinline__ void mmqp(floatx4 (&acc)[8][4],
                                     const bf16x8 (&wf)[2][2],
                                     const bf16x8 (&xf)[4][2]) {
    __builtin_amdgcn_s_setprio(1);
#pragma unroll
    for (int i = 0; i < 2; ++i)
#pragma unroll
        for (int ni = 0; ni < 4; ++ni)
#pragma unroll
            for (int kk = 0; kk < 2; ++kk)
                acc[2 * P + i][ni] = __builtin_amdgcn_mfma_f32_16x16x32_bf16(
                    wf[i][kk], xf[ni][kk], acc[2 * P + i][ni], 0, 0, 0);
    __builtin_amdgcn_s_setprio(0);
}

template <typename TC>
__global__ __launch_bounds__(512, 2) void gemm8p(
    const bf16* __restrict__ A, const bf16* __restrict__ W,
    TC* __restrict__ C, int K, int lda, int ldc)
{
    __shared__ __align__(16) bf16 smem[65536];          // 128 KB

    const int tid  = threadIdx.x;
    const int lane = tid & 63;
    const int w    = tid >> 6;       // 0..7
    const int wm4  = w & 3;          // m-quarter
    const int wn2  = w >> 2;         // n-half
    const int col  = lane & 15;
    const int quad = lane >> 4;
    const int cx   = col & 7;

    const int m0 = blockIdx.x * 256;
    const int n0 = blockIdx.y * 256;

    bf16* sAp[2][2], *sBp[2][2];
#pragma unroll
    for (int b = 0; b < 2; ++b)
#pragma unroll
        for (int h = 0; h < 2; ++h) {
            sAp[b][h] = smem + (b * 2 + h) * 8192;
            sBp[b][h] = smem + 32768 + (b * 2 + h) * 8192;
        }

    const bf16* Ab = A + (size_t)m0 * lda;
    const bf16* Wb = W + (size_t)n0 * K;

    floatx4 acc[8][4] = {};
    bf16x8 xf[4][2], wf[2][2];

    const int hx  = wm4 & 1;         // the wave's A-half
    const int wmh = wm4 >> 1;        // row group within that half
    const int T   = K / 64;

    // Prologue: tile0 {A0,A1,B0,B1}; entry invariant: A,B0 done; B1 2 out.
    stage_half<64>(Ab, lda, 0, sAp[0][0], 0, tid);
    stage_half<64>(Ab, lda, 0, sAp[0][1], 1, tid);
    stage_half<32>(Wb, K,   0, sBp[0][0], 0, tid);
    stage_half<32>(Wb, K,   0, sBp[0][1], 1, tid);
    VMCNT(2);
    SBAR();

    for (int t = 0; t < T; ++t) {
        const int b = t & 1;
        const int kt1 = (t + 1) * 64;

        // P0: x-frags (8) + W mi{0,1} from B-half0 (4); stage A0,A1(t+1).
        ld_x8(sAp[b][hx], wmh, col, quad, cx, xf);
        ld_w2(sBp[b][0], wn2 * 64, col, quad, cx, wf);
        if (t + 1 < T) {
            stage_half<64>(Ab, lda, kt1, sAp[b ^ 1][0], 0, tid);
            stage_half<64>(Ab, lda, kt1, sAp[b ^ 1][1], 1, tid);
        }
        SBAR();
        LGKM0();
        mmqp<0>(acc, wf, xf);
        if (t + 1 < T) { VMCNT(4); } else { VMCNT(0); }   // B1(t) complete
        SBAR();

        // P1: W mi{2,3} from B-half1; stage B0(t+1).
        ld_w2(sBp[b][1], wn2 * 64, col, quad, cx, wf);
        if (t + 1 < T) stage_half<32>(Wb, K, kt1, sBp[b ^ 1][0], 0, tid);
        SBAR();
        LGKM0();
        mmqp<1>(acc, wf, xf);
        SBAR();

        // P2: W mi{4,5} from B-half0 (still resident); stage B1(t+1).
        ld_w2(sBp[b][0], wn2 * 64 + 32, col, quad, cx, wf);
        if (t + 1 < T) stage_half<32>(Wb, K, kt1, sBp[b ^ 1][1], 1, tid);
        SBAR();
        LGKM0();
        mmqp<2>(acc, wf, xf);
        SBAR();

        // P3: W mi{6,7} from B-half1; counted wait: A,B0(t+1) complete.
        ld_w2(sBp[b][1], wn2 * 64 + 32, col, quad, cx, wf);
        SBAR();
        LGKM0();
        mmqp<3>(acc, wf, xf);
        VMCNT(2);
        SBAR();
    }

    // Epilogue. D frag (mi,ni): C[m = m0+wm4*64+ni*16+col]
    //                            [n = n0+wn2*128+mi*16+quad*4+r], r=0..3.
    if constexpr (sizeof(TC) == 2) {
        // bf16: LDS C-tile [256][256] (128KB), 8B chunks, phys j = j^(m&15).
#pragma unroll
        for (int mi = 0; mi < 8; ++mi)
#pragma unroll
            for (int ni = 0; ni < 4; ++ni) {
                union { bf16 h4[4]; uint2 u; } pk;
#pragma unroll
                for (int r = 0; r < 4; ++r) pk.h4[r] = (bf16)acc[mi][ni][r];
                const int ml = wm4 * 64 + ni * 16 + col;
                const int j  = wn2 * 32 + mi * 4 + quad;
                *(uint2*)&smem[ml * 256 + (j ^ (ml & 15)) * 4] = pk.u;
            }
        __syncthreads();
#pragma unroll
        for (int it = 0; it < 32; ++it) {
            const int m  = it * 8 + w;
            const int jp = lane ^ (m & 15);
            const uint2 d = *(const uint2*)&smem[m * 256 + jp * 4];
            *(uint2*)&C[(size_t)(m0 + m) * ldc + n0 + lane * 4] = d;
        }
    } else {
        // f32: direct dwordx4 (4 consecutive n per lane, 64B runs per row).
#pragma unroll
        for (int mi = 0; mi < 8; ++mi)
#pragma unroll
            for (int ni = 0; ni < 4; ++ni) {
                const int m  = m0 + wm4 * 64 + ni * 16 + col;
                const int nn = n0 + wn2 * 128 + mi * 16 + quad * 4;
                *(floatx4*)&C[(size_t)m * ldc + nn] = acc[mi][ni];
            }
    }
}

// ---------- R3 fallback GEMM (fp32-or-bf16 in, register staging) ----------
template <typename TA, typename TB, typename TC>
__global__ __launch_bounds__(256, 2) void gemm_bt(
    const TA* __restrict__ A, const TB* __restrict__ W,
    TC* __restrict__ C, int M, int N, int K)
{
    __shared__ __align__(16) bf16 sA[BM * BK];
    __shared__ __align__(16) bf16 sB[BN * BK];

    const int tid  = threadIdx.x;
    const int lane = tid & 63;
    const int w    = tid >> 6;
    const int wm   = w >> 1;
    const int wn   = w & 1;
    const int m0   = blockIdx.x * BM;
    const int n0   = blockIdx.y * BN;
    const int col  = lane & 15;
    const int quad = lane >> 4;

    floatx4 acc[4][4] = {};

    for (int kt = 0; kt < K; kt += BK) {
        bf16x8 ga[2], gb[2];
#pragma unroll
        for (int i = 0; i < 2; ++i) {
            const int c   = i * 256 + tid;
            const int row = c >> 2;
            const int kc  = c & 3;
            ga[i] = load8(&A[(size_t)(m0 + row) * K + kt + kc * 8]);
            gb[i] = load8(&W[(size_t)(n0 + row) * K + kt + kc * 8]);
        }
        __syncthreads();
#pragma unroll
        for (int i = 0; i < 2; ++i) {
            const int c = i * 256 + tid;
            *(bf16x8*)&sA[c * 8] = ga[i];
            *(bf16x8*)&sB[c * 8] = gb[i];
        }
        __syncthreads();

        bf16x8 af[4], bfr[4];
#pragma unroll
        for (int mi = 0; mi < 4; ++mi)
            af[mi] = *(const bf16x8*)&sA[(wm * 64 + mi * 16 + col) * BK + quad * 8];
#pragma unroll
        for (int ni = 0; ni < 4; ++ni)
            bfr[ni] = *(const bf16x8*)&sB[(wn * 64 + ni * 16 + col) * BK + quad * 8];

#pragma unroll
        for (int mi = 0; mi < 4; ++mi)
#pragma unroll
            for (int ni = 0; ni < 4; ++ni)
                acc[mi][ni] = __builtin_amdgcn_mfma_f32_16x16x32_bf16(
                    af[mi], bfr[ni], acc[mi][ni], 0, 0, 0);
    }

#pragma unroll
    for (int mi = 0; mi < 4; ++mi) {
#pragma unroll
        for (int r = 0; r < 4; ++r) {
            const int row = m0 + wm * 64 + mi * 16 + quad * 4 + r;
#pragma unroll
            for (int ni = 0; ni < 4; ++ni) {
                const int cc = n0 + wn * 64 + ni * 16 + col;
                C[(size_t)row * N + cc] = (TC)acc[mi][ni][r];
            }
        }
    }
}

// ---------- per-token head-mixing attention ----------
// One wave per token. qkv row staged to LDS via global_load_lds (swizzled
// source, linear dest); per-wave vmcnt; NO barriers anywhere.
__global__ __launch_bounds__(256) void attn_heads(
    bf16* base, size_t koff, size_t voff, int stride, bf16* ob)
{
    __shared__ __align__(16) bf16 sQ[4][3072];       // [wave] q|k|v, 48x64
    __shared__ __align__(16) bf16 sP[4][16 * 40];    // [wave] P, pad-40 rows
    __shared__ __align__(16) bf16 sO[4][1024];       // [wave] O-tile, 8B swz

    const int tid   = threadIdx.x;
    const int lane  = tid & 63;
    const int w     = tid >> 6;
    const int token = blockIdx.x * 4 + w;
    const int col   = lane & 15;
    const int quad  = lane >> 4;

    bf16* qt = base + (size_t)token * stride;
    const bf16* src0 = qt;
    const bf16* src1 = qt + koff;
    const bf16* src2 = qt + voff;
    bf16* ot = ob + (size_t)token * HIDDEN;

    // Stage 6KB: rows 0..15 = Q[h][d], 16..31 = K, 32..47 = V (64-elem rows,
    // phys chunk c holds global chunk c^(row&7); source pre-swizzled).
#pragma unroll
    for (int i = 0; i < 6; ++i) {
        const int ci = i * 64 + lane;              // linear 16B chunk 0..383
        const int rl = (ci >> 3) & 15;             // row within region
        const int cs = (ci & 7) ^ (rl & 7);
        const bf16* s = (i < 2) ? src0 : (i < 4) ? src1 : src2;
        async_load16(&s[(rl * 8 + cs) * 8], &sQ[w][ci * 8]);
    }
    VMCNT(0);

    // S = Q K^T : conflict-free swizzled b128 frag reads.
    bf16x8 qa[2], kb[2];
#pragma unroll
    for (int kk = 0; kk < 2; ++kk) {
        const int c = ((kk << 2) + quad) ^ (col & 7);
        qa[kk] = *(const bf16x8*)&sQ[w][(col * 8 + c) * 8];
        kb[kk] = *(const bf16x8*)&sQ[w][((16 + col) * 8 + c) * 8];
    }
    floatx4 s = {};
    s = __builtin_amdgcn_mfma_f32_16x16x32_bf16(qa[0], kb[0], s, 0, 0, 0);
    s = __builtin_amdgcn_mfma_f32_16x16x32_bf16(qa[1], kb[1], s, 0, 0, 0);

    // PV A-frag (operand swap): va[dt][j] = V[g=quad*8+j][d=dt*16+col],
    // quad>=2 is k-padding (zeros both sides).
    bf16x8 va[4] = {};
    if (quad < 2) {
#pragma unroll
        for (int dt = 0; dt < 4; ++dt) {
            const int cb = dt * 2 + (col >> 3);
#pragma unroll
            for (int j = 0; j < 8; ++j) {
                const int r = 32 + quad * 8 + j;
                va[dt][j] = sQ[w][(r * 8 + (cb ^ j)) * 8 + (col & 7)];
            }
        }
    }

    // Max-free softmax over g (S/8 ~ N(0,1); fp32-safe).
#pragma unroll
    for (int r = 0; r < 4; ++r) {
        float e = __expf(s[r] * 0.125f);
        float su = e;
#pragma unroll
        for (int off = 1; off < 16; off <<= 1)
            su += __shfl_xor(su, off);
        sP[w][(quad * 4 + r) * 40 + col] = (bf16)(e / su);
    }

    // O = P V with swap: D -> O[h=col][d=dt*16+quad*4+r] (d-contiguous).
    bf16x8 pa = {};
    if (quad < 2) pa = *(const bf16x8*)&sP[w][col * 40 + quad * 8];
#pragma unroll
    for (int dt = 0; dt < 4; ++dt) {
        floatx4 o4 = {};
        o4 = __builtin_amdgcn_mfma_f32_16x16x32_bf16(va[dt], pa, o4, 0, 0, 0);
        union { bf16 h4[4]; uint2 u; } pk;
#pragma unroll
        for (int r = 0; r < 4; ++r) pk.h4[r] = (bf16)o4[r];
        const int c8 = dt * 4 + quad;
        *(uint2*)&sO[w][(col * 16 + (c8 ^ col)) * 4] = pk.u;
    }

    // Coalesced O out: 4 x (64 lanes x 8B) = 512B runs.
#pragma unroll
    for (int it = 0; it < 4; ++it) {
        const int n8 = it * 64 + lane;
        const int h = n8 >> 4, c8 = n8 & 15;
        const uint2 d = *(const uint2*)&sO[w][(h * 16 + (c8 ^ h)) * 4];
        *(uint2*)&ot[n8 * 4] = d;
    }
}

extern "C" void kernel_launch(void* const* d_in, const int* in_sizes, int n_in,
                              void* d_out, int out_size, void* d_ws, size_t ws_size,
                              hipStream_t stream) {
    const float* x  = (const float*)d_in[0];
    const float* wq = (const float*)d_in[1];
    const float* wk = (const float*)d_in[2];
    const float* wv = (const float*)d_in[3];
    const float* wo = (const float*)d_in[4];
    float* out = (float*)d_out;

    const int M = in_sizes[0] / HIDDEN;   // 16384 tokens
    const size_t MH = (size_t)M * HIDDEN;
    const size_t WH = (size_t)HIDDEN * HIDDEN;

    const size_t need = (MH + 4 * WH + (size_t)M * 3 * HIDDEN) * sizeof(bf16);

    if (ws_size >= need && (M % 256) == 0) {
        // Fast path: convert once, 8-phase bf16 GEMMs.
        bf16* xb  = (bf16*)d_ws;          // [M][1024]; reused as O after QKV
        bf16* wpk = xb + MH;              // [4][1024][1024] packed q|k|v|o
        bf16* qkv = wpk + 4 * WH;         // [M][3072]

        const int mh8 = (int)(MH / 8);
        const int nchunks = mh8 + (int)(4 * WH / 8);
        cvt_all<<<dim3(nchunks / 256), 256, 0, stream>>>(x, wq, wk, wv, wo,
                                                         xb, wpk, mh8);

        gemm8p<bf16><<<dim3(M / 256, 3 * HIDDEN / 256), 512, 0, stream>>>(
            xb, wpk, qkv, HIDDEN, HIDDEN, 3 * HIDDEN);

        // xb is dead now; attn writes O into it (dense lda=1024 for Wo GEMM).
        attn_heads<<<dim3(M / 4), 256, 0, stream>>>(qkv, 1024, 2048,
                                                    3 * HIDDEN, xb);

        gemm8p<float><<<dim3(M / 256, HIDDEN / 256), 512, 0, stream>>>(
            xb, wpk + 3 * WH, out, HIDDEN, HIDDEN, HIDDEN);
    } else {
        // R3 proven fallback (needs 100.7 MB).
        bf16* qb = (bf16*)d_ws;
        bf16* kb = qb + MH;
        bf16* vb = kb + MH;
        dim3 grid(M / BM, HIDDEN / BN), block(256);
        gemm_bt<float, float, bf16><<<grid, block, 0, stream>>>(x, wq, qb, M, HIDDEN, HIDDEN);
        gemm_bt<float, float, bf16><<<grid, block, 0, stream>>>(x, wk, kb, M, HIDDEN, HIDDEN);
        gemm_bt<float, float, bf16><<<grid, block, 0, stream>>>(x, wv, vb, M, HIDDEN, HIDDEN);
        attn_heads<<<dim3(M / 4), block, 0, stream>>>(qb, MH, 2 * MH, HIDDEN, qb);
        gemm_bt<bf16, float, float><<<grid, block, 0, stream>>>(qb, wo, out, M, HIDDEN, HIDDEN);
    }
}

// Round 4
// 290.653 us; speedup vs baseline: 1.4810x; 1.4810x over previous
//
#include <hip/hip_runtime.h>
#include <hip/hip_bf16.h>

// Problem: B=4,S=4096 tokens (16384), HIDDEN=1024, 16 heads x 64 dim.
// "Attention" mixes HEADS per token (16x16 softmax over heads), not sequence.
// Inputs/output fp32; compute bf16-MFMA w/ fp32 accumulate.
//
// R8 -> R9 (R8: 430us -- operand-swap GEMM regressed QKV 125->210us,
// MfmaUtil 19.7%, conflicts 1.79M; runtime-indexed LDS pointer arrays +
// tight vmcnt + scatter epilogue all violated proven discipline):
//  GEMM: byte-exact revert to R6's gemm8p (proven 116.6us QKV, MfmaUtil 38%,
//  FETCH 73.8MB, conflicts 0). Fenced barriers + per-phase VMCNT(8) measured
//  BEST of the three sync variants tried (116.6 < 125 bare-bar < 210 swap).
//  No XCD swizzle (R7 measured it +28% FETCH on this grid).
//  ATTN: keep R8's rewrite (the one sound R8 piece): 6KB token row staged
//  via 6 global_load_lds (wave-uniform dest + lane*16 -- the legal form),
//  per-wave vmcnt(0), zero barriers, swizzled conflict-light frag reads,
//  512B-coalesced O stores. ~10 VMEM instr/wave vs ~56 in the R5-R7 attn
//  (which was ~95-107us by subtraction vs ~20us traffic floor).

typedef __bf16 bf16;
typedef __attribute__((ext_vector_type(8))) __bf16 bf16x8;
typedef __attribute__((ext_vector_type(4))) float floatx4;

#define HIDDEN 1024
#define BM 128
#define BN 128
#define BK 32

#define FENCE() asm volatile("" ::: "memory")
#define BAR()                                                                  \
    do {                                                                       \
        FENCE();                                                               \
        __builtin_amdgcn_s_barrier();                                          \
        FENCE();                                                               \
    } while (0)
#define VMCNT(N) asm volatile("s_waitcnt vmcnt(" #N ")" ::: "memory")

__device__ __forceinline__ void async_load16(const bf16* g, bf16* lds) {
    __builtin_amdgcn_global_load_lds(
        (const __attribute__((address_space(1))) void*)g,
        (__attribute__((address_space(3))) void*)lds, 16, 0, 0);
}

__device__ __forceinline__ bf16x8 load8(const bf16* p) {
    return *(const bf16x8*)p;
}
__device__ __forceinline__ bf16x8 load8(const float* p) {
    floatx4 lo = *(const floatx4*)p;
    floatx4 hi = *(const floatx4*)(p + 4);
    bf16x8 r;
#pragma unroll
    for (int i = 0; i < 4; ++i) { r[i] = (bf16)lo[i]; r[i + 4] = (bf16)hi[i]; }
    return r;
}

// ---------- one-time fp32 -> bf16 conversion: x then packed wq|wk|wv|wo ----
__global__ __launch_bounds__(256) void cvt_all(
    const float* __restrict__ x,
    const float* __restrict__ wq, const float* __restrict__ wk,
    const float* __restrict__ wv, const float* __restrict__ wo,
    bf16* __restrict__ xb, bf16* __restrict__ wpk, int mh8)
{
    const int per = (HIDDEN * HIDDEN) / 8;   // 131072 chunks per weight
    int i = blockIdx.x * 256 + threadIdx.x;
    if (i < mh8) {
        *(bf16x8*)&xb[(size_t)i * 8] = load8(&x[(size_t)i * 8]);
    } else {
        int j = i - mh8;
        int wsel = j / per;
        int off  = (j - wsel * per) * 8;
        const float* s = wsel == 0 ? wq : wsel == 1 ? wk : wsel == 2 ? wv : wo;
        *(bf16x8*)&wpk[(size_t)j * 8] = load8(&s[off]);
    }
}

// ---------- 256^2 8-phase GEMM (R6 exact: proven 116.6us) ----------------
// C[m,n] = sum_k A[m,k]*W[n,k]. 512 thr = 8 waves (2M x 4N), wave tile
// 128x64, acc[8][4] 16x16 frags. LDS 128KB: [dbuf2][half2][128x64] x {A,B}.

// stage one 16KB half-tile (2 x global_load_lds/thread, linear LDS dest,
// inverse-swizzled global source). S=64 for A-halves, S=32 for B-halves.
template <int S>
__device__ __forceinline__ void stage_half(const bf16* __restrict__ gbase,
                                           int ld, int kt, bf16* lhalf,
                                           int h, int tid) {
#pragma unroll
    for (int j = 0; j < 2; ++j) {
        const int ci = j * 512 + tid;
        const int rr = ci >> 3;
        const int cs = (ci & 7) ^ (rr & 7);
        const int gr = h * S + (rr & (S - 1)) + (rr >> (S == 64 ? 6 : 5)) * (2 * S);
        async_load16(&gbase[(size_t)gr * ld + kt + cs * 8], &lhalf[ci * 8]);
    }
}

// frag reads from a half (both k-chunks), swizzled: chunk=(kk*4+quad)^(col&7)
__device__ __forceinline__ void ld_a4(const bf16* h, int wm, int col, int quad,
                                      int cx, bf16x8* a) {
#pragma unroll
    for (int i = 0; i < 4; ++i) {
        const int rr = i * 16 + col + (wm << 6);
#pragma unroll
        for (int kk = 0; kk < 2; ++kk)
            a[i * 2 + kk] =
                *(const bf16x8*)&h[rr * 64 + (((kk << 2) + quad) ^ cx) * 8];
    }
}
__device__ __forceinline__ void ld_b2(const bf16* h, int wn, int col, int quad,
                                      int cx, bf16x8* b) {
#pragma unroll
    for (int j = 0; j < 2; ++j) {
        const int rr = j * 16 + col + (wn << 5);
#pragma unroll
        for (int kk = 0; kk < 2; ++kk)
            b[j * 2 + kk] =
                *(const bf16x8*)&h[rr * 64 + (((kk << 2) + quad) ^ cx) * 8];
    }
}

template <int H, int G>
__device__ __forceinline__ void mmq(floatx4 (&acc)[8][4], const bf16x8 (&a)[8],
                                    const bf16x8 (&bb)[4]) {
    __builtin_amdgcn_s_setprio(1);
#pragma unroll
    for (int i = 0; i < 4; ++i)
#pragma unroll
        for (int j = 0; j < 2; ++j)
#pragma unroll
            for (int kk = 0; kk < 2; ++kk)
                acc[H * 4 + i][G * 2 + j] =
                    __builtin_amdgcn_mfma_f32_16x16x32_bf16(
                        a[i * 2 + kk], bb[j * 2 + kk],
                        acc[H * 4 + i][G * 2 + j], 0, 0, 0);
    __builtin_amdgcn_s_setprio(0);
}

template <typename TC>
__global__ __launch_bounds__(512, 2) void gemm8p(
    const bf16* __restrict__ A, const bf16* __restrict__ W,
    TC* __restrict__ C, int K, int lda, int ldc)
{
    __shared__ __align__(16) bf16 sA[2][2][128 * 64];   // 64 KB
    __shared__ __align__(16) bf16 sB[2][2][128 * 64];   // 64 KB

    const int tid  = threadIdx.x;
    const int lane = tid & 63;
    const int w    = tid >> 6;       // 0..7
    const int wm   = w >> 2;         // 0..1
    const int wn   = w & 3;          // 0..3
    const int m0   = blockIdx.x * 256;
    const int n0   = blockIdx.y * 256;
    const int col  = lane & 15;
    const int quad = lane >> 4;
    const int cx   = col & 7;

    const bf16* Ab = A + (size_t)m0 * lda;
    const bf16* Wb = W + (size_t)n0 * K;

    floatx4 acc[8][4] = {};
    bf16x8 a[8], b0[4], b1[4];

    const int T = K / 64;

    // Prologue: tile0 {A0,B0,B1,A1} + tile1 {A0,B0,B1}  (14 loads/thread).
    stage_half<64>(Ab, lda, 0, sA[0][0], 0, tid);
    stage_half<32>(Wb, K,   0, sB[0][0], 0, tid);
    stage_half<32>(Wb, K,   0, sB[0][1], 1, tid);
    stage_half<64>(Ab, lda, 0, sA[0][1], 1, tid);
    if (T > 1) {
        stage_half<64>(Ab, lda, 64, sA[1][0], 0, tid);
        stage_half<32>(Wb, K,   64, sB[1][0], 0, tid);
        stage_half<32>(Wb, K,   64, sB[1][1], 1, tid);
        VMCNT(6);                    // first 8 done = tile0 complete
    } else {
        VMCNT(0);
    }
    BAR();

    for (int t = 0; t < T; ++t) {
        const int b   = t & 1;
        const int kt1 = (t + 1) * 64;
        const int kt2 = (t + 2) * 64;

        // P0: quad(0,0). reads A0(t), B0(t); stages A1(t+1).
        ld_a4(sA[b][0], wm, col, quad, cx, a);
        ld_b2(sB[b][0], wn, col, quad, cx, b0);
        if (t + 1 < T) stage_half<64>(Ab, lda, kt1, sA[b ^ 1][1], 1, tid);
        VMCNT(8);
        BAR();
        mmq<0, 0>(acc, a, b0);
        BAR();

        // P1: quad(0,1). reads B1(t); stages A0(t+2) over A0(t).
        ld_b2(sB[b][1], wn, col, quad, cx, b1);
        if (t + 2 < T) stage_half<64>(Ab, lda, kt2, sA[b][0], 0, tid);
        VMCNT(8);
        BAR();
        mmq<0, 1>(acc, a, b1);
        BAR();

        // P2: quad(1,1). reads A1(t); stages B0(t+2) over B0(t).
        ld_a4(sA[b][1], wm, col, quad, cx, a);
        if (t + 2 < T) {
            stage_half<32>(Wb, K, kt2, sB[b][0], 0, tid);
        }
        VMCNT(8);
        BAR();
        mmq<1, 1>(acc, a, b1);
        BAR();

        // P3: quad(1,0). no reads (b0 kept in regs); stages B1(t+2).
        if (t + 2 < T) {
            stage_half<32>(Wb, K, kt2, sB[b][1], 1, tid);
            VMCNT(8);
        } else {
            VMCNT(0);                // drain tail (t=T-2 covers tile T-1)
        }
        BAR();
        mmq<1, 0>(acc, a, b0);
        BAR();
    }

#pragma unroll
    for (int mi = 0; mi < 8; ++mi) {
#pragma unroll
        for (int r = 0; r < 4; ++r) {
            const int row = m0 + wm * 128 + mi * 16 + quad * 4 + r;
#pragma unroll
            for (int ni = 0; ni < 4; ++ni) {
                const int cc = n0 + wn * 64 + ni * 16 + col;
                C[(size_t)row * ldc + cc] = (TC)acc[mi][ni][r];
            }
        }
    }
}

// ---------- R3 fallback GEMM (fp32-or-bf16 in, register staging) ----------
template <typename TA, typename TB, typename TC>
__global__ __launch_bounds__(256, 2) void gemm_bt(
    const TA* __restrict__ A, const TB* __restrict__ W,
    TC* __restrict__ C, int M, int N, int K)
{
    __shared__ __align__(16) bf16 sA[BM * BK];
    __shared__ __align__(16) bf16 sB[BN * BK];

    const int tid  = threadIdx.x;
    const int lane = tid & 63;
    const int w    = tid >> 6;
    const int wm   = w >> 1;
    const int wn   = w & 1;
    const int m0   = blockIdx.x * BM;
    const int n0   = blockIdx.y * BN;
    const int col  = lane & 15;
    const int quad = lane >> 4;

    floatx4 acc[4][4] = {};

    for (int kt = 0; kt < K; kt += BK) {
        bf16x8 ga[2], gb[2];
#pragma unroll
        for (int i = 0; i < 2; ++i) {
            const int c   = i * 256 + tid;
            const int row = c >> 2;
            const int kc  = c & 3;
            ga[i] = load8(&A[(size_t)(m0 + row) * K + kt + kc * 8]);
            gb[i] = load8(&W[(size_t)(n0 + row) * K + kt + kc * 8]);
        }
        __syncthreads();
#pragma unroll
        for (int i = 0; i < 2; ++i) {
            const int c = i * 256 + tid;
            *(bf16x8*)&sA[c * 8] = ga[i];
            *(bf16x8*)&sB[c * 8] = gb[i];
        }
        __syncthreads();

        bf16x8 af[4], bfr[4];
#pragma unroll
        for (int mi = 0; mi < 4; ++mi)
            af[mi] = *(const bf16x8*)&sA[(wm * 64 + mi * 16 + col) * BK + quad * 8];
#pragma unroll
        for (int ni = 0; ni < 4; ++ni)
            bfr[ni] = *(const bf16x8*)&sB[(wn * 64 + ni * 16 + col) * BK + quad * 8];

#pragma unroll
        for (int mi = 0; mi < 4; ++mi)
#pragma unroll
            for (int ni = 0; ni < 4; ++ni)
                acc[mi][ni] = __builtin_amdgcn_mfma_f32_16x16x32_bf16(
                    af[mi], bfr[ni], acc[mi][ni], 0, 0, 0);
    }

#pragma unroll
    for (int mi = 0; mi < 4; ++mi) {
#pragma unroll
        for (int r = 0; r < 4; ++r) {
            const int row = m0 + wm * 64 + mi * 16 + quad * 4 + r;
#pragma unroll
            for (int ni = 0; ni < 4; ++ni) {
                const int cc = n0 + wn * 64 + ni * 16 + col;
                C[(size_t)row * N + cc] = (TC)acc[mi][ni][r];
            }
        }
    }
}

// ---------- per-token head-mixing attention (R8 design, kept) ------------
// One wave per token. qkv row staged to LDS via global_load_lds (swizzled
// source, linear dest = wave-uniform + lane*16); per-wave vmcnt; NO barriers.
__global__ __launch_bounds__(256) void attn_heads(
    bf16* base, size_t koff, size_t voff, int stride, bf16* ob)
{
    __shared__ __align__(16) bf16 sQ[4][3072];       // [wave] q|k|v, 48x64
    __shared__ __align__(16) bf16 sP[4][16 * 40];    // [wave] P, pad-40 rows
    __shared__ __align__(16) bf16 sO[4][1024];       // [wave] O-tile, 8B swz

    const int tid   = threadIdx.x;
    const int lane  = tid & 63;
    const int w     = tid >> 6;
    const int token = blockIdx.x * 4 + w;
    const int col   = lane & 15;
    const int quad  = lane >> 4;

    bf16* qt = base + (size_t)token * stride;
    const bf16* src0 = qt;
    const bf16* src1 = qt + koff;
    const bf16* src2 = qt + voff;
    bf16* ot = ob + (size_t)token * HIDDEN;

    // Stage 6KB: rows 0..15 = Q[h][d], 16..31 = K, 32..47 = V (64-elem rows,
    // phys chunk c holds global chunk c^(row&7); source pre-swizzled).
#pragma unroll
    for (int i = 0; i < 6; ++i) {
        const int ci = i * 64 + lane;              // linear 16B chunk 0..383
        const int rl = (ci >> 3) & 15;             // row within region
        const int cs = (ci & 7) ^ (rl & 7);
        const bf16* s = (i < 2) ? src0 : (i < 4) ? src1 : src2;
        async_load16(&s[(rl * 8 + cs) * 8], &sQ[w][ci * 8]);
    }
    VMCNT(0);

    // S = Q K^T : conflict-free swizzled b128 frag reads.
    bf16x8 qa[2], kb[2];
#pragma unroll
    for (int kk = 0; kk < 2; ++kk) {
        const int c = ((kk << 2) + quad) ^ (col & 7);
        qa[kk] = *(const bf16x8*)&sQ[w][(col * 8 + c) * 8];
        kb[kk] = *(const bf16x8*)&sQ[w][((16 + col) * 8 + c) * 8];
    }
    floatx4 s = {};
    s = __builtin_amdgcn_mfma_f32_16x16x32_bf16(qa[0], kb[0], s, 0, 0, 0);
    s = __builtin_amdgcn_mfma_f32_16x16x32_bf16(qa[1], kb[1], s, 0, 0, 0);

    // PV A-frag (operand swap): va[dt][j] = V[g=quad*8+j][d=dt*16+col],
    // quad>=2 is k-padding (zeros both sides).
    bf16x8 va[4] = {};
    if (quad < 2) {
#pragma unroll
        for (int dt = 0; dt < 4; ++dt) {
            const int cb = dt * 2 + (col >> 3);
#pragma unroll
            for (int j = 0; j < 8; ++j) {
                const int r = 32 + quad * 8 + j;
                va[dt][j] = sQ[w][(r * 8 + (cb ^ j)) * 8 + (col & 7)];
            }
        }
    }

    // Max-free softmax over g (S/8 ~ N(0,1); fp32-safe).
#pragma unroll
    for (int r = 0; r < 4; ++r) {
        float e = __expf(s[r] * 0.125f);
        float su = e;
#pragma unroll
        for (int off = 1; off < 16; off <<= 1)
            su += __shfl_xor(su, off);
        sP[w][(quad * 4 + r) * 40 + col] = (bf16)(e / su);
    }

    // O = P V with swap: D -> O[h=col][d=dt*16+quad*4+r] (d-contiguous).
    bf16x8 pa = {};
    if (quad < 2) pa = *(const bf16x8*)&sP[w][col * 40 + quad * 8];
#pragma unroll
    for (int dt = 0; dt < 4; ++dt) {
        floatx4 o4 = {};
        o4 = __builtin_amdgcn_mfma_f32_16x16x32_bf16(va[dt], pa, o4, 0, 0, 0);
        union { bf16 h4[4]; uint2 u; } pk;
#pragma unroll
        for (int r = 0; r < 4; ++r) pk.h4[r] = (bf16)o4[r];
        const int c8 = dt * 4 + quad;
        *(uint2*)&sO[w][(col * 16 + (c8 ^ col)) * 4] = pk.u;
    }

    // Coalesced O out: 4 x (64 lanes x 8B) = 512B runs.
#pragma unroll
    for (int it = 0; it < 4; ++it) {
        const int n8 = it * 64 + lane;
        const int h = n8 >> 4, c8 = n8 & 15;
        const uint2 d = *(const uint2*)&sO[w][(h * 16 + (c8 ^ h)) * 4];
        *(uint2*)&ot[n8 * 4] = d;
    }
}

extern "C" void kernel_launch(void* const* d_in, const int* in_sizes, int n_in,
                              void* d_out, int out_size, void* d_ws, size_t ws_size,
                              hipStream_t stream) {
    const float* x  = (const float*)d_in[0];
    const float* wq = (const float*)d_in[1];
    const float* wk = (const float*)d_in[2];
    const float* wv = (const float*)d_in[3];
    const float* wo = (const float*)d_in[4];
    float* out = (float*)d_out;

    const int M = in_sizes[0] / HIDDEN;   // 16384 tokens
    const size_t MH = (size_t)M * HIDDEN;
    const size_t WH = (size_t)HIDDEN * HIDDEN;

    const size_t need = (MH + 4 * WH + (size_t)M * 3 * HIDDEN) * sizeof(bf16);

    if (ws_size >= need && (M % 256) == 0) {
        // Fast path: convert once, 8-phase bf16 GEMMs.
        bf16* xb  = (bf16*)d_ws;          // [M][1024]; reused as O after QKV
        bf16* wpk = xb + MH;              // [4][1024][1024] packed q|k|v|o
        bf16* qkv = wpk + 4 * WH;         // [M][3072]

        const int mh8 = (int)(MH / 8);
        const int nchunks = mh8 + (int)(4 * WH / 8);
        cvt_all<<<dim3(nchunks / 256), 256, 0, stream>>>(x, wq, wk, wv, wo,
                                                         xb, wpk, mh8);

        gemm8p<bf16><<<dim3(M / 256, 3 * HIDDEN / 256), 512, 0, stream>>>(
            xb, wpk, qkv, HIDDEN, HIDDEN, 3 * HIDDEN);

        // xb is dead now; attn writes O into it (dense lda=1024 for Wo GEMM).
        attn_heads<<<dim3(M / 4), 256, 0, stream>>>(qkv, 1024, 2048,
                                                    3 * HIDDEN, xb);

        gemm8p<float><<<dim3(M / 256, HIDDEN / 256), 512, 0, stream>>>(
            xb, wpk + 3 * WH, out, HIDDEN, HIDDEN, HIDDEN);
    } else {
        // R3 proven fallback (needs 100.7 MB).
        bf16* qb = (bf16*)d_ws;
        bf16* kb = qb + MH;
        bf16* vb = kb + MH;
        dim3 grid(M / BM, HIDDEN / BN), block(256);
        gemm_bt<float, float, bf16><<<grid, block, 0, stream>>>(x, wq, qb, M, HIDDEN, HIDDEN);
        gemm_bt<float, float, bf16><<<grid, block, 0, stream>>>(x, wk, kb, M, HIDDEN, HIDDEN);
        gemm_bt<float, float, bf16><<<grid, block, 0, stream>>>(x, wv, vb, M, HIDDEN, HIDDEN);
        attn_heads<<<dim3(M / 4), block, 0, stream>>>(qb, MH, 2 * MH, HIDDEN, qb);
        gemm_bt<bf16, float, float><<<grid, block, 0, stream>>>(qb, wo, out, M, HIDDEN, HIDDEN);
    }
}